// Round 1
// baseline (493.467 us; speedup 1.0000x reference)
//
#include <hip/hip_runtime.h>

typedef unsigned short u16;
typedef unsigned int u32;
typedef __attribute__((ext_vector_type(8))) short s16x8;
typedef __attribute__((ext_vector_type(4))) float f32x4;

#define Bq 4
#define Tq 2048
#define Cq 1024
#define Hq 16
#define Dq 64

__device__ __forceinline__ u16 f2bf(float f) {
    union { float f; u32 u; } v; v.f = f;
    u32 r = v.u + 0x7FFF + ((v.u >> 16) & 1);
    return (u16)(r >> 16);
}

// ---------------- cast fp32 -> bf16 (contiguous) ----------------
__global__ __launch_bounds__(256) void cast_f32_bf16(const float* __restrict__ in,
                                                     u16* __restrict__ out) {
    size_t i = ((size_t)blockIdx.x * 256 + threadIdx.x) * 4;
    float4 f = *(const float4*)(in + i);
    u16 o[4] = { f2bf(f.x), f2bf(f.y), f2bf(f.z), f2bf(f.w) };
    *(ulonglong1*)0; // no-op guard removed below
    *(unsigned long long*)(out + i) =
        (unsigned long long)o[0] | ((unsigned long long)o[1] << 16) |
        ((unsigned long long)o[2] << 32) | ((unsigned long long)o[3] << 48);
}

// ---------------- transpose + cast: in[rows][cols] f32 -> out[cols][rows] bf16 ----
__global__ __launch_bounds__(256) void transpose_cast(const float* __restrict__ in,
                                                      u16* __restrict__ out,
                                                      int rows, int cols) {
    __shared__ float tile[32][33];
    int c0 = blockIdx.x * 32, r0 = blockIdx.y * 32;
    int tx = threadIdx.x, ty = threadIdx.y; // 32 x 8
    for (int i = 0; i < 32; i += 8)
        tile[ty + i][tx] = in[(size_t)(r0 + ty + i) * cols + (c0 + tx)];
    __syncthreads();
    for (int i = 0; i < 32; i += 8)
        out[(size_t)(c0 + ty + i) * rows + (r0 + tx)] = f2bf(tile[tx][ty + i]);
}

// ---------------- GEMM: C[M][N] = A[M][K] * BT[N][K]^T + bias[N] ----------------
#define BM 64
#define BN 64
#define BK 32
#define LDT 40  // padded LDS row stride (elements)

template<bool OUT_BF16>
__global__ __launch_bounds__(256) void gemm_bt(const u16* __restrict__ A,
                                               const u16* __restrict__ BT,
                                               const float* __restrict__ bias,
                                               void* __restrict__ Cout,
                                               int M, int N, int K) {
    __shared__ u16 As[BM * LDT];
    __shared__ u16 Bs[BN * LDT];
    int n0 = blockIdx.x * BN, m0 = blockIdx.y * BM;
    int tid = threadIdx.x;
    int lane = tid & 63, w = tid >> 6;
    int wm = (w >> 1) * 32, wn = (w & 1) * 32;
    int row16 = lane & 15, quad = lane >> 4;

    f32x4 acc[2][2] = {};

    int srow = tid >> 2;
    int scol = (tid & 3) * 8;
    const u16* Aptr = A + (size_t)(m0 + srow) * K + scol;
    const u16* Bptr = BT + (size_t)(n0 + srow) * K + scol;
    u16* As_w = &As[srow * LDT + scol];
    u16* Bs_w = &Bs[srow * LDT + scol];

    for (int k0 = 0; k0 < K; k0 += BK) {
        s16x8 av = *(const s16x8*)(Aptr + k0);
        s16x8 bv = *(const s16x8*)(Bptr + k0);
        __syncthreads();
        *(s16x8*)As_w = av;
        *(s16x8*)Bs_w = bv;
        __syncthreads();
        s16x8 af[2], bf[2];
        af[0] = *(const s16x8*)&As[(wm + row16) * LDT + quad * 8];
        af[1] = *(const s16x8*)&As[(wm + 16 + row16) * LDT + quad * 8];
        bf[0] = *(const s16x8*)&Bs[(wn + row16) * LDT + quad * 8];
        bf[1] = *(const s16x8*)&Bs[(wn + 16 + row16) * LDT + quad * 8];
#pragma unroll
        for (int mi = 0; mi < 2; mi++)
#pragma unroll
            for (int ni = 0; ni < 2; ni++)
                acc[mi][ni] = __builtin_amdgcn_mfma_f32_16x16x32_bf16(
                    af[mi], bf[ni], acc[mi][ni], 0, 0, 0);
    }

#pragma unroll
    for (int mi = 0; mi < 2; mi++)
#pragma unroll
        for (int ni = 0; ni < 2; ni++) {
            int col = n0 + wn + ni * 16 + row16;
            float bv = bias[col];
#pragma unroll
            for (int r = 0; r < 4; r++) {
                int rowg = m0 + wm + mi * 16 + quad * 4 + r;
                float vv = acc[mi][ni][r] + bv;
                if (OUT_BF16)
                    ((u16*)Cout)[(size_t)rowg * N + col] = f2bf(vv);
                else
                    ((float*)Cout)[(size_t)rowg * N + col] = vv;
            }
        }
}

// ---------------- flash attention (causal) ----------------
// qkv: [B*T][3C] bf16 ; y: [B*T][C] bf16
#define ALD 72  // padded LDS row stride

__global__ __launch_bounds__(256) void attn_kernel(const u16* __restrict__ qkv,
                                                   u16* __restrict__ y) {
    __shared__ u16 Ks[64 * ALD];
    __shared__ u16 Vt[64 * ALD];
    __shared__ u16 Ps[4][16 * ALD];

    int tid = threadIdx.x;
    int lane = tid & 63, w = tid >> 6;
    int row16 = lane & 15, quad = lane >> 4;
    int qblk = gridDim.x - 1 - blockIdx.x;  // longest-running blocks first
    int bh = blockIdx.y;
    int b = bh >> 4, h = bh & 15;
    int q0 = qblk * 64;
    const u16* base = qkv + (size_t)b * Tq * 3072;

    // Q fragments (A-layout), held in registers for the whole kernel
    int qrow = q0 + w * 16 + row16;
    const u16* qp = base + (size_t)qrow * 3072 + h * 64 + quad * 8;
    s16x8 qf0 = *(const s16x8*)(qp);
    s16x8 qf1 = *(const s16x8*)(qp + 32);

    float m_run[4], l_run[4];
    f32x4 acc_o[4] = {};
#pragma unroll
    for (int r = 0; r < 4; r++) { m_run[r] = -__builtin_inff(); l_run[r] = 0.f; }

    int skey = tid & 63;
    int sd = (tid >> 6) * 16;
    const float scale = 0.125f;  // 1/sqrt(64)

    int nkb = qblk + 1;
    for (int kb = 0; kb < nkb; kb++) {
        int k0 = kb * 64;
        const u16* Krow = base + (size_t)(k0 + skey) * 3072 + 1024 + h * 64 + sd;
        const u16* Vrow = base + (size_t)(k0 + skey) * 3072 + 2048 + h * 64 + sd;
        s16x8 kv0 = *(const s16x8*)(Krow);
        s16x8 kv1 = *(const s16x8*)(Krow + 8);
        s16x8 vv0 = *(const s16x8*)(Vrow);
        s16x8 vv1 = *(const s16x8*)(Vrow + 8);
        __syncthreads();
        *(s16x8*)&Ks[skey * ALD + sd] = kv0;
        *(s16x8*)&Ks[skey * ALD + sd + 8] = kv1;
#pragma unroll
        for (int i = 0; i < 8; i++) {
            Vt[(sd + i) * ALD + skey] = (u16)vv0[i];
            Vt[(sd + 8 + i) * ALD + skey] = (u16)vv1[i];
        }
        __syncthreads();

        // scores S = Q K^T  (16 x 64 per wave)
        f32x4 s[4];
#pragma unroll
        for (int nk = 0; nk < 4; nk++) {
            s16x8 kf0 = *(const s16x8*)&Ks[(nk * 16 + row16) * ALD + quad * 8];
            s16x8 kf1 = *(const s16x8*)&Ks[(nk * 16 + row16) * ALD + 32 + quad * 8];
            f32x4 z = {};
            z = __builtin_amdgcn_mfma_f32_16x16x32_bf16(qf0, kf0, z, 0, 0, 0);
            z = __builtin_amdgcn_mfma_f32_16x16x32_bf16(qf1, kf1, z, 0, 0, 0);
            s[nk] = z;
        }

        // mask + scale + row max
        float mx[4];
        int qi = q0 + w * 16 + quad * 4;
#pragma unroll
        for (int r = 0; r < 4; r++) mx[r] = -__builtin_inff();
#pragma unroll
        for (int nk = 0; nk < 4; nk++) {
            int kj = k0 + nk * 16 + row16;
#pragma unroll
            for (int r = 0; r < 4; r++) {
                float v = s[nk][r] * scale;
                v = (kj <= qi + r) ? v : -__builtin_inff();
                s[nk][r] = v;
                mx[r] = fmaxf(mx[r], v);
            }
        }
#pragma unroll
        for (int off = 1; off < 16; off <<= 1)
#pragma unroll
            for (int r = 0; r < 4; r++)
                mx[r] = fmaxf(mx[r], __shfl_xor(mx[r], off, 64));

        float alpha[4], rs[4];
#pragma unroll
        for (int r = 0; r < 4; r++) {
            float mn = fmaxf(m_run[r], mx[r]);
            alpha[r] = __expf(m_run[r] - mn);
            m_run[r] = mn;
            rs[r] = 0.f;
        }
#pragma unroll
        for (int nk = 0; nk < 4; nk++)
#pragma unroll
            for (int r = 0; r < 4; r++) {
                float p = __expf(s[nk][r] - m_run[r]);
                s[nk][r] = p;
                rs[r] += p;
            }
#pragma unroll
        for (int off = 1; off < 16; off <<= 1)
#pragma unroll
            for (int r = 0; r < 4; r++) rs[r] += __shfl_xor(rs[r], off, 64);
#pragma unroll
        for (int r = 0; r < 4; r++) l_run[r] = l_run[r] * alpha[r] + rs[r];
#pragma unroll
        for (int nd = 0; nd < 4; nd++)
#pragma unroll
            for (int r = 0; r < 4; r++) acc_o[nd][r] *= alpha[r];

        // P (C-layout) -> LDS -> A-layout fragments
        u16* Pw = Ps[w];
#pragma unroll
        for (int nk = 0; nk < 4; nk++)
#pragma unroll
            for (int r = 0; r < 4; r++)
                Pw[(quad * 4 + r) * ALD + nk * 16 + row16] = f2bf(s[nk][r]);

#pragma unroll
        for (int kk = 0; kk < 2; kk++) {
            s16x8 pf = *(const s16x8*)&Pw[row16 * ALD + kk * 32 + quad * 8];
#pragma unroll
            for (int nd = 0; nd < 4; nd++) {
                s16x8 vf = *(const s16x8*)&Vt[(nd * 16 + row16) * ALD + kk * 32 + quad * 8];
                acc_o[nd] = __builtin_amdgcn_mfma_f32_16x16x32_bf16(pf, vf, acc_o[nd], 0, 0, 0);
            }
        }
        __syncthreads();
    }

    // epilogue: O / l -> y (bf16, [B,T,C] with head offset)
    int t0 = q0 + w * 16 + quad * 4;
#pragma unroll
    for (int nd = 0; nd < 4; nd++) {
        int col = h * 64 + nd * 16 + row16;
#pragma unroll
        for (int r = 0; r < 4; r++) {
            float o = acc_o[nd][r] / l_run[r];
            y[((size_t)b * Tq + t0 + r) * 1024 + col] = f2bf(o);
        }
    }
}

extern "C" void kernel_launch(void* const* d_in, const int* in_sizes, int n_in,
                              void* d_out, int out_size, void* d_ws, size_t ws_size,
                              hipStream_t stream) {
    const float* x      = (const float*)d_in[0];
    const float* w_qkv  = (const float*)d_in[1];
    const float* b_qkv  = (const float*)d_in[2];
    const float* w_proj = (const float*)d_in[3];
    const float* b_proj = (const float*)d_in[4];
    float* out = (float*)d_out;

    u16* ws     = (u16*)d_ws;
    u16* x_bf   = ws;                               // 8192*1024
    u16* wqkvT  = x_bf  + (size_t)8192 * 1024;      // 3072*1024
    u16* wprojT = wqkvT + (size_t)3072 * 1024;      // 1024*1024
    u16* qkv    = wprojT + (size_t)1024 * 1024;     // 8192*3072
    u16* ybf    = qkv   + (size_t)8192 * 3072;      // 8192*1024

    cast_f32_bf16<<<dim3(8192), dim3(256), 0, stream>>>(x, x_bf);
    transpose_cast<<<dim3(3072 / 32, 1024 / 32), dim3(32, 8), 0, stream>>>(w_qkv, wqkvT, 1024, 3072);
    transpose_cast<<<dim3(1024 / 32, 1024 / 32), dim3(32, 8), 0, stream>>>(w_proj, wprojT, 1024, 1024);
    gemm_bt<true><<<dim3(3072 / BN, 8192 / BM), 256, 0, stream>>>(x_bf, wqkvT, b_qkv, (void*)qkv, 8192, 3072, 1024);
    attn_kernel<<<dim3(32, 64), 256, 0, stream>>>(qkv, ybf);
    gemm_bt<false><<<dim3(1024 / BN, 8192 / BM), 256, 0, stream>>>(ybf, wprojT, b_proj, (void*)out, 8192, 1024, 1024);
}

// Round 2
// 323.519 us; speedup vs baseline: 1.5253x; 1.5253x over previous
//
#include <hip/hip_runtime.h>

typedef unsigned short u16;
typedef unsigned int u32;
typedef __attribute__((ext_vector_type(8))) short s16x8;
typedef __attribute__((ext_vector_type(4))) float f32x4;

#define Bq 4
#define Tq 2048

#if __has_builtin(__builtin_amdgcn_exp2f)
#define EXP2(x) __builtin_amdgcn_exp2f(x)
#else
#define EXP2(x) __expf((x) * 0.69314718f)
#endif

#if __has_builtin(__builtin_amdgcn_rcpf)
#define RCP(x) __builtin_amdgcn_rcpf(x)
#else
#define RCP(x) (1.0f / (x))
#endif

#define GLL(gp, lp) __builtin_amdgcn_global_load_lds(                         \
    (const __attribute__((address_space(1))) unsigned int*)(const void*)(gp), \
    (__attribute__((address_space(3))) unsigned int*)(void*)(lp), 16, 0, 0)

__device__ __forceinline__ u16 f2bf(float f) {
    union { float f; u32 u; } v; v.f = f;
    u32 r = v.u + 0x7FFF + ((v.u >> 16) & 1);
    return (u16)(r >> 16);
}

__device__ __forceinline__ float bf2f(u16 b) {
    union { u32 u; float f; } v; v.u = ((u32)b) << 16;
    return v.f;
}

__device__ __forceinline__ s16x8 scale_frag(s16x8 v, float s) {
    s16x8 o;
#pragma unroll
    for (int i = 0; i < 8; i++) o[i] = (short)f2bf(bf2f((u16)v[i]) * s);
    return o;
}

// ---------------- cast fp32 -> bf16 (contiguous) ----------------
__global__ __launch_bounds__(256) void cast_f32_bf16(const float* __restrict__ in,
                                                     u16* __restrict__ out) {
    size_t i = ((size_t)blockIdx.x * 256 + threadIdx.x) * 4;
    float4 f = *(const float4*)(in + i);
    u16 o[4] = { f2bf(f.x), f2bf(f.y), f2bf(f.z), f2bf(f.w) };
    *(unsigned long long*)(out + i) =
        (unsigned long long)o[0] | ((unsigned long long)o[1] << 16) |
        ((unsigned long long)o[2] << 32) | ((unsigned long long)o[3] << 48);
}

// ---------------- transpose + cast: in[rows][cols] f32 -> out[cols][rows] bf16 ----
__global__ __launch_bounds__(256) void transpose_cast(const float* __restrict__ in,
                                                      u16* __restrict__ out,
                                                      int rows, int cols) {
    __shared__ float tile[32][33];
    int c0 = blockIdx.x * 32, r0 = blockIdx.y * 32;
    int tx = threadIdx.x, ty = threadIdx.y; // 32 x 8
    for (int i = 0; i < 32; i += 8)
        tile[ty + i][tx] = in[(size_t)(r0 + ty + i) * cols + (c0 + tx)];
    __syncthreads();
    for (int i = 0; i < 32; i += 8)
        out[(size_t)(c0 + ty + i) * rows + (r0 + tx)] = f2bf(tile[tx][ty + i]);
}

// ---------------- V transpose: qkv V-part [b][t][c] -> vT[b*1024 + c][t] (bf16) ----
__global__ __launch_bounds__(256) void vtrans(const u16* __restrict__ qkv,
                                              u16* __restrict__ vT) {
    __shared__ u16 tile[32][33];
    int c0 = blockIdx.x * 32, t0 = blockIdx.y * 32, b = blockIdx.z;
    int tx = threadIdx.x, ty = threadIdx.y; // 32 x 8
    const u16* src = qkv + (size_t)b * 2048 * 3072 + 2048;
#pragma unroll
    for (int i = 0; i < 32; i += 8)
        tile[ty + i][tx] = src[(size_t)(t0 + ty + i) * 3072 + c0 + tx];
    __syncthreads();
    u16* dst = vT + (size_t)b * 1024 * 2048;
#pragma unroll
    for (int i = 0; i < 32; i += 8)
        dst[(size_t)(c0 + ty + i) * 2048 + t0 + tx] = tile[tx][ty + i];
}

// ---------------- GEMM (m97-style): C[M][N] = A[M][K]*BT[N][K]^T + bias ----------
// 128x128 tile, BK=32, global_load_lds staging, 4 waves each 64x64.
template<bool OUT_BF16>
__global__ __launch_bounds__(256) void gemm128(const u16* __restrict__ A,
                                               const u16* __restrict__ BT,
                                               const float* __restrict__ bias,
                                               void* __restrict__ Cout,
                                               int M, int N, int K) {
    __shared__ u16 As[128 * 32];
    __shared__ u16 Bs[128 * 32];
    int n0 = blockIdx.x * 128, m0 = blockIdx.y * 128;
    int tid = threadIdx.x, lane = tid & 63, w = tid >> 6;
    int row16 = lane & 15, quad = lane >> 4;
    int wm = (w >> 1) * 64, wn = (w & 1) * 64;

    f32x4 acc[4][4] = {};

    // staging: chunk id = j*256 + tid ; row = id>>2, kc = id&3 ; LDS = chunk*16B
    int c0 = tid, c1 = 256 + tid;
    const u16* Ag0 = A + (size_t)(m0 + (c0 >> 2)) * K + (c0 & 3) * 8;
    const u16* Ag1 = A + (size_t)(m0 + (c1 >> 2)) * K + (c1 & 3) * 8;
    const u16* Bg0 = BT + (size_t)(n0 + (c0 >> 2)) * K + (c0 & 3) * 8;
    const u16* Bg1 = BT + (size_t)(n0 + (c1 >> 2)) * K + (c1 & 3) * 8;
    u16* Al0 = As + (size_t)(w * 64) * 8;         // wave-uniform LDS bases
    u16* Al1 = As + (size_t)(256 + w * 64) * 8;
    u16* Bl0 = Bs + (size_t)(w * 64) * 8;
    u16* Bl1 = Bs + (size_t)(256 + w * 64) * 8;

    for (int k0 = 0; k0 < K; k0 += 32) {
        __syncthreads();
        GLL(Ag0 + k0, Al0);
        GLL(Ag1 + k0, Al1);
        GLL(Bg0 + k0, Bl0);
        GLL(Bg1 + k0, Bl1);
        __syncthreads();
        s16x8 af[4], bfr[4];
#pragma unroll
        for (int mi = 0; mi < 4; mi++)
            af[mi] = *(const s16x8*)&As[(wm + mi * 16 + row16) * 32 + quad * 8];
#pragma unroll
        for (int ni = 0; ni < 4; ni++)
            bfr[ni] = *(const s16x8*)&Bs[(wn + ni * 16 + row16) * 32 + quad * 8];
#pragma unroll
        for (int mi = 0; mi < 4; mi++)
#pragma unroll
            for (int ni = 0; ni < 4; ni++)
                acc[mi][ni] = __builtin_amdgcn_mfma_f32_16x16x32_bf16(
                    af[mi], bfr[ni], acc[mi][ni], 0, 0, 0);
    }

#pragma unroll
    for (int ni = 0; ni < 4; ni++) {
        int col = n0 + wn + ni * 16 + row16;
        float bv = bias[col];
#pragma unroll
        for (int mi = 0; mi < 4; mi++)
#pragma unroll
            for (int r = 0; r < 4; r++) {
                int rowg = m0 + wm + mi * 16 + quad * 4 + r;
                float vv = acc[mi][ni][r] + bv;
                if (OUT_BF16)
                    ((u16*)Cout)[(size_t)rowg * N + col] = f2bf(vv);
                else
                    ((float*)Cout)[(size_t)rowg * N + col] = vv;
            }
    }
}

// ---------------- flash attention (causal, no-max softmax) ----------------
// qkv: [B*T][3C] bf16 ; vT: [b*1024 + h*64 + d][T] bf16 ; y: [B*T][C] bf16
#define KLD 72
#define VLD 72
#define PLD 72

__global__ __launch_bounds__(256) void attn_kernel(const u16* __restrict__ qkv,
                                                   const u16* __restrict__ vT,
                                                   u16* __restrict__ y) {
    __shared__ u16 Ks[64 * KLD];
    __shared__ u16 Vt[64 * VLD];
    __shared__ u16 Ps[4][32 * PLD];

    int tid = threadIdx.x;
    int lane = tid & 63, w = tid >> 6;
    int row16 = lane & 15, quad = lane >> 4;
    int qblk = gridDim.x - 1 - blockIdx.x;  // longest blocks first
    int bh = blockIdx.y;
    int b = bh >> 4, h = bh & 15;
    int q0 = qblk * 128;
    const u16* base = qkv + (size_t)b * Tq * 3072;

    const float qscale = 0.125f * 1.44269504f;  // 1/sqrt(64) * log2(e)

    // Q fragments (A-layout), pre-scaled, in registers for whole kernel
    s16x8 qf[2][2];
#pragma unroll
    for (int mi = 0; mi < 2; mi++) {
        int qrow = q0 + w * 32 + mi * 16 + row16;
        const u16* qp = base + (size_t)qrow * 3072 + h * 64 + quad * 8;
        qf[mi][0] = scale_frag(*(const s16x8*)qp, qscale);
        qf[mi][1] = scale_frag(*(const s16x8*)(qp + 32), qscale);
    }

    f32x4 acc_o[2][4] = {};
    f32x4 acc_l[2] = {};
    s16x8 ones;
#pragma unroll
    for (int i = 0; i < 8; i++) ones[i] = (short)0x3F80;  // bf16 1.0

    int srow = tid >> 2, sc = (tid & 3) * 16;
    const u16* Kp0 = base + (size_t)srow * 3072 + 1024 + h * 64 + sc;
    const u16* Vp0 = vT + ((size_t)bh * 64 + srow) * 2048 + sc;
    u16* Ksw = &Ks[srow * KLD + sc];
    u16* Vtw = &Vt[srow * VLD + sc];
    u16* Psw = Ps[w];

    int nkb = 2 * qblk + 2;
    for (int kb = 0; kb < nkb; kb++) {
        int k0 = kb * 64;
        s16x8 ka = *(const s16x8*)(Kp0 + (size_t)k0 * 3072);
        s16x8 kb2 = *(const s16x8*)(Kp0 + (size_t)k0 * 3072 + 8);
        s16x8 va = *(const s16x8*)(Vp0 + k0);
        s16x8 vb = *(const s16x8*)(Vp0 + k0 + 8);
        __syncthreads();
        *(s16x8*)Ksw = ka;
        *(s16x8*)(Ksw + 8) = kb2;
        *(s16x8*)Vtw = va;
        *(s16x8*)(Vtw + 8) = vb;
        __syncthreads();

        if (k0 <= q0 + w * 32 + 31) {  // wave-uniform: skip fully-masked blocks
            f32x4 s[2][4];
#pragma unroll
            for (int nk = 0; nk < 4; nk++) {
                s16x8 kf0 = *(const s16x8*)&Ks[(nk * 16 + row16) * KLD + quad * 8];
                s16x8 kf1 = *(const s16x8*)&Ks[(nk * 16 + row16) * KLD + 32 + quad * 8];
#pragma unroll
                for (int mi = 0; mi < 2; mi++) {
                    f32x4 z = {};
                    z = __builtin_amdgcn_mfma_f32_16x16x32_bf16(qf[mi][0], kf0, z, 0, 0, 0);
                    z = __builtin_amdgcn_mfma_f32_16x16x32_bf16(qf[mi][1], kf1, z, 0, 0, 0);
                    s[mi][nk] = z;
                }
            }
            if (kb >= 2 * qblk) {  // only diagonal region needs the causal mask
#pragma unroll
                for (int mi = 0; mi < 2; mi++) {
                    int rowb = q0 + w * 32 + mi * 16 + quad * 4;
#pragma unroll
                    for (int nk = 0; nk < 4; nk++) {
                        int kj = k0 + nk * 16 + row16;
#pragma unroll
                        for (int r = 0; r < 4; r++)
                            if (kj > rowb + r) s[mi][nk][r] = -__builtin_inff();
                    }
                }
            }
            // exp2 (scale*log2e folded into Q; scores bounded -> no max needed)
#pragma unroll
            for (int mi = 0; mi < 2; mi++)
#pragma unroll
                for (int nk = 0; nk < 4; nk++)
#pragma unroll
                    for (int r = 0; r < 4; r++) {
                        float p = EXP2(s[mi][nk][r]);
                        Psw[(mi * 16 + quad * 4 + r) * PLD + nk * 16 + row16] = f2bf(p);
                    }
            // P(A-layout) x V^T(B-layout); row-sums via MFMA against ones
#pragma unroll
            for (int kk = 0; kk < 2; kk++) {
                s16x8 pf[2];
#pragma unroll
                for (int mi = 0; mi < 2; mi++)
                    pf[mi] = *(const s16x8*)&Psw[(mi * 16 + row16) * PLD + kk * 32 + quad * 8];
#pragma unroll
                for (int nd = 0; nd < 4; nd++) {
                    s16x8 vf = *(const s16x8*)&Vt[(nd * 16 + row16) * VLD + kk * 32 + quad * 8];
#pragma unroll
                    for (int mi = 0; mi < 2; mi++)
                        acc_o[mi][nd] = __builtin_amdgcn_mfma_f32_16x16x32_bf16(
                            pf[mi], vf, acc_o[mi][nd], 0, 0, 0);
                }
#pragma unroll
                for (int mi = 0; mi < 2; mi++)
                    acc_l[mi] = __builtin_amdgcn_mfma_f32_16x16x32_bf16(
                        pf[mi], ones, acc_l[mi], 0, 0, 0);
            }
        }
    }

    // epilogue: O / l -> y bf16
#pragma unroll
    for (int mi = 0; mi < 2; mi++) {
        int t0 = q0 + w * 32 + mi * 16 + quad * 4;
#pragma unroll
        for (int r = 0; r < 4; r++) {
            float inv = RCP(acc_l[mi][r]);
#pragma unroll
            for (int nd = 0; nd < 4; nd++) {
                int col = h * 64 + nd * 16 + row16;
                y[((size_t)b * Tq + t0 + r) * 1024 + col] = f2bf(acc_o[mi][nd][r] * inv);
            }
        }
    }
}

extern "C" void kernel_launch(void* const* d_in, const int* in_sizes, int n_in,
                              void* d_out, int out_size, void* d_ws, size_t ws_size,
                              hipStream_t stream) {
    const float* x      = (const float*)d_in[0];
    const float* w_qkv  = (const float*)d_in[1];
    const float* b_qkv  = (const float*)d_in[2];
    const float* w_proj = (const float*)d_in[3];
    const float* b_proj = (const float*)d_in[4];
    float* out = (float*)d_out;

    u16* ws     = (u16*)d_ws;
    u16* x_bf   = ws;                               // 8192*1024 (reused as vT later)
    u16* wqkvT  = x_bf  + (size_t)8192 * 1024;      // 3072*1024
    u16* wprojT = wqkvT + (size_t)3072 * 1024;      // 1024*1024
    u16* qkv    = wprojT + (size_t)1024 * 1024;     // 8192*3072
    u16* ybf    = qkv   + (size_t)8192 * 3072;      // 8192*1024
    u16* vT     = x_bf;                             // alias: x_bf dead after GEMM1

    cast_f32_bf16<<<dim3(8192), dim3(256), 0, stream>>>(x, x_bf);
    transpose_cast<<<dim3(96, 32), dim3(32, 8), 0, stream>>>(w_qkv, wqkvT, 1024, 3072);
    transpose_cast<<<dim3(32, 32), dim3(32, 8), 0, stream>>>(w_proj, wprojT, 1024, 1024);
    gemm128<true><<<dim3(24, 64), 256, 0, stream>>>(x_bf, wqkvT, b_qkv, (void*)qkv, 8192, 3072, 1024);
    vtrans<<<dim3(32, 64, 4), dim3(32, 8), 0, stream>>>(qkv, vT);
    attn_kernel<<<dim3(16, 64), 256, 0, stream>>>(qkv, vT, ybf);
    gemm128<false><<<dim3(8, 64), 256, 0, stream>>>(ybf, wprojT, b_proj, (void*)out, 8192, 1024, 1024);
}

// Round 3
// 262.670 us; speedup vs baseline: 1.8787x; 1.2317x over previous
//
#include <hip/hip_runtime.h>

typedef unsigned short u16;
typedef unsigned int u32;
typedef unsigned long long u64;
typedef __attribute__((ext_vector_type(8))) short s16x8;
typedef __attribute__((ext_vector_type(4))) float f32x4;

#if __has_builtin(__builtin_amdgcn_exp2f)
#define EXP2(x) __builtin_amdgcn_exp2f(x)
#else
#define EXP2(x) __expf((x) * 0.69314718f)
#endif

#if __has_builtin(__builtin_amdgcn_rcpf)
#define RCP(x) __builtin_amdgcn_rcpf(x)
#else
#define RCP(x) (1.0f / (x))
#endif

#define GLL(gp, lp) __builtin_amdgcn_global_load_lds(                         \
    (const __attribute__((address_space(1))) unsigned int*)(const void*)(gp), \
    (__attribute__((address_space(3))) unsigned int*)(void*)(lp), 16, 0, 0)

__device__ __forceinline__ u16 f2bf(float f) {
    union { float f; u32 u; } v; v.f = f;
    u32 r = v.u + 0x7FFF + ((v.u >> 16) & 1);
    return (u16)(r >> 16);
}

__device__ __forceinline__ float bf2f(u16 b) {
    union { u32 u; float f; } v; v.u = ((u32)b) << 16;
    return v.f;
}

__device__ __forceinline__ s16x8 scale_frag(s16x8 v, float s) {
    s16x8 o;
#pragma unroll
    for (int i = 0; i < 8; i++) o[i] = (short)f2bf(bf2f((u16)v[i]) * s);
    return o;
}

// ---------------- cast fp32 -> bf16 (contiguous) ----------------
__global__ __launch_bounds__(256) void cast_f32_bf16(const float* __restrict__ in,
                                                     u16* __restrict__ out) {
    size_t i = ((size_t)blockIdx.x * 256 + threadIdx.x) * 4;
    float4 f = *(const float4*)(in + i);
    u16 o[4] = { f2bf(f.x), f2bf(f.y), f2bf(f.z), f2bf(f.w) };
    *(unsigned long long*)(out + i) =
        (unsigned long long)o[0] | ((unsigned long long)o[1] << 16) |
        ((unsigned long long)o[2] << 32) | ((unsigned long long)o[3] << 48);
}

// ---------------- transpose + cast: in[rows][cols] f32 -> out[cols][rows] bf16 ----
__global__ __launch_bounds__(256) void transpose_cast(const float* __restrict__ in,
                                                      u16* __restrict__ out,
                                                      int rows, int cols) {
    __shared__ float tile[32][33];
    int c0 = blockIdx.x * 32, r0 = blockIdx.y * 32;
    int tx = threadIdx.x, ty = threadIdx.y; // 32 x 8
    for (int i = 0; i < 32; i += 8)
        tile[ty + i][tx] = in[(size_t)(r0 + ty + i) * cols + (c0 + tx)];
    __syncthreads();
    for (int i = 0; i < 32; i += 8)
        out[(size_t)(c0 + ty + i) * rows + (r0 + tx)] = f2bf(tile[tx][ty + i]);
}

// ---------------- GEMM: C = A[M][K] * BT[N][K]^T + bias, BK=64, XOR-swizzled LDS ---
// MODE 0: fp32 out to O1[M][N].
// MODE 1: QKV split -- col<2048 -> bf16 qk[M][2048]; col>=2048 -> vT[(b*1024+c)][2048]
template<int MODE>
__global__ __launch_bounds__(256, 3) void gemm_bt64(const u16* __restrict__ A,
                                                    const u16* __restrict__ BT,
                                                    const float* __restrict__ bias,
                                                    void* __restrict__ O1,
                                                    u16* __restrict__ vT,
                                                    int M, int N, int K) {
    __shared__ u16 As[128 * 64];
    __shared__ u16 Bs[128 * 64];
    int n0 = blockIdx.x * 128, m0 = blockIdx.y * 128;
    int tid = threadIdx.x, lane = tid & 63, w = tid >> 6;
    int row16 = lane & 15, quad = lane >> 4;
    int wm = (w >> 1) * 64, wn = (w & 1) * 64;
    f32x4 acc[4][4] = {};

    int lr = lane >> 3;            // row-in-8 (== row&7 of staged row)
    int cswz = (lane & 7) ^ lr;    // swizzled source column chunk
    const u16* Ag = A + (size_t)(m0 + w * 32 + lr) * K + cswz * 8;
    const u16* Bg = BT + (size_t)(n0 + w * 32 + lr) * K + cswz * 8;
    u16* Asl = As + (w * 32) * 64;
    u16* Bsl = Bs + (w * 32) * 64;

    for (int k0 = 0; k0 < K; k0 += 64) {
        __syncthreads();
#pragma unroll
        for (int j = 0; j < 4; j++) {
            GLL(Ag + k0 + (size_t)j * 8 * K, Asl + j * 8 * 64);
            GLL(Bg + k0 + (size_t)j * 8 * K, Bsl + j * 8 * 64);
        }
        __syncthreads();
#pragma unroll
        for (int kk = 0; kk < 2; kk++) {
            s16x8 af[4], bf[4];
#pragma unroll
            for (int mi = 0; mi < 4; mi++)
                af[mi] = *(const s16x8*)&As[(wm + mi * 16 + row16) * 64 +
                                            (((kk * 4 + quad) ^ (row16 & 7)) * 8)];
#pragma unroll
            for (int ni = 0; ni < 4; ni++)
                bf[ni] = *(const s16x8*)&Bs[(wn + ni * 16 + row16) * 64 +
                                            (((kk * 4 + quad) ^ (row16 & 7)) * 8)];
#pragma unroll
            for (int mi = 0; mi < 4; mi++)
#pragma unroll
                for (int ni = 0; ni < 4; ni++)
                    acc[mi][ni] = __builtin_amdgcn_mfma_f32_16x16x32_bf16(
                        af[mi], bf[ni], acc[mi][ni], 0, 0, 0);
        }
    }

#pragma unroll
    for (int ni = 0; ni < 4; ni++) {
        int col = n0 + wn + ni * 16 + row16;
        float bv = bias[col];
        if (MODE == 0) {
            float* O = (float*)O1;
#pragma unroll
            for (int mi = 0; mi < 4; mi++)
#pragma unroll
                for (int r = 0; r < 4; r++)
                    O[(size_t)(m0 + wm + mi * 16 + quad * 4 + r) * N + col] =
                        acc[mi][ni][r] + bv;
        } else {
            if (col < 2048) {
                u16* qk = (u16*)O1;
#pragma unroll
                for (int mi = 0; mi < 4; mi++)
#pragma unroll
                    for (int r = 0; r < 4; r++)
                        qk[(size_t)(m0 + wm + mi * 16 + quad * 4 + r) * 2048 + col] =
                            f2bf(acc[mi][ni][r] + bv);
            } else {
                int c = col - 2048;
#pragma unroll
                for (int mi = 0; mi < 4; mi++) {
                    int t0 = m0 + wm + mi * 16 + quad * 4;
                    int b = t0 >> 11;
                    u16 o0 = f2bf(acc[mi][ni][0] + bv);
                    u16 o1 = f2bf(acc[mi][ni][1] + bv);
                    u16 o2 = f2bf(acc[mi][ni][2] + bv);
                    u16 o3 = f2bf(acc[mi][ni][3] + bv);
                    u64 pack = (u64)o0 | ((u64)o1 << 16) | ((u64)o2 << 32) | ((u64)o3 << 48);
                    *(u64*)&vT[((size_t)(b * 1024) + c) * 2048 + (t0 & 2047)] = pack;
                }
            }
        }
    }
}

// ---------------- flash attention (causal, no-max softmax, paired q-tiles) -------
// qk: [B*T][2048] bf16 (Q cols 0..1023, K cols 1024..2047)
// vT: [(b*1024 + h*64 + d)][2048] bf16 ; y: [B*T][1024] bf16
// block = pair (qt=pairi, qt=31-pairi) of 64-row q-tiles -> uniform 33 iters.
__global__ __launch_bounds__(256, 4) void attn_kernel(const u16* __restrict__ qk,
                                                      const u16* __restrict__ vT,
                                                      u16* __restrict__ y) {
    __shared__ u16 Kb[2][64 * 64];
    __shared__ u16 Vb[2][64 * 64];
    __shared__ u16 Ps[4 * 16 * 64];

    int tid = threadIdx.x, lane = tid & 63, w = tid >> 6;
    int row16 = lane & 15, quad = lane >> 4;
    int pairi = blockIdx.x;            // 0..15
    int bh = blockIdx.y;
    int b = bh >> 4, h = bh & 15;
    const u16* qkb = qk + (size_t)b * 2048 * 2048;
    const u16* vtb = vT + ((size_t)(b * 1024) + h * 64) * 2048;

    int lr = lane >> 3, cswz = (lane & 7) ^ lr;
    const u16* Kg = qkb + (size_t)(w * 16 + lr) * 2048 + 1024 + h * 64 + cswz * 8;
    const u16* Vg = vtb + (size_t)(w * 16 + lr) * 2048 + cswz * 8;
    u16* Psw = Ps + w * 1024;
    int sw = row16 & 7;

    s16x8 ones;
#pragma unroll
    for (int i = 0; i < 8; i++) ones[i] = (short)0x3F80;  // bf16 1.0
    const float qs = 0.125f * 1.44269504f;                // 1/sqrt(64) * log2(e)

    for (int half = 0; half < 2; half++) {
        int qt = half ? pairi : (31 - pairi);  // big tile first
        int q0 = qt * 64;
        int niter = qt + 1;

        int qrow = q0 + w * 16 + row16;
        const u16* qp = qkb + (size_t)qrow * 2048 + h * 64 + quad * 8;
        s16x8 qf0 = scale_frag(*(const s16x8*)qp, qs);
        s16x8 qf1 = scale_frag(*(const s16x8*)(qp + 32), qs);

        f32x4 acc_o[4] = {};
        f32x4 acc_l = {};

        __syncthreads();  // all waves done reading K/V buffers of previous half
#pragma unroll
        for (int j = 0; j < 2; j++) {  // prologue prefetch k-block 0 -> buf 0
            GLL(Kg + (size_t)j * 8 * 2048, Kb[0] + w * 16 * 64 + j * 8 * 64);
            GLL(Vg + (size_t)j * 8 * 2048, Vb[0] + w * 16 * 64 + j * 8 * 64);
        }

        for (int kb = 0; kb < niter; kb++) {
            int cur = kb & 1;
            __syncthreads();  // drains this wave's GLLs for cur (vmcnt 0) + joins
            if (kb + 1 < niter) {
                int k1 = (kb + 1) * 64;
#pragma unroll
                for (int j = 0; j < 2; j++) {
                    GLL(Kg + (size_t)(k1 + j * 8) * 2048, Kb[cur ^ 1] + w * 16 * 64 + j * 8 * 64);
                    GLL(Vg + k1 + (size_t)j * 8 * 2048, Vb[cur ^ 1] + w * 16 * 64 + j * 8 * 64);
                }
            }
            const u16* Kc = Kb[cur];
            const u16* Vc = Vb[cur];
            int k0 = kb * 64;

            f32x4 s[4];
#pragma unroll
            for (int nk = 0; nk < 4; nk++) {
                s16x8 kf0 = *(const s16x8*)&Kc[(nk * 16 + row16) * 64 + ((quad ^ sw) * 8)];
                s16x8 kf1 = *(const s16x8*)&Kc[(nk * 16 + row16) * 64 + (((4 + quad) ^ sw) * 8)];
                f32x4 z = {};
                z = __builtin_amdgcn_mfma_f32_16x16x32_bf16(qf0, kf0, z, 0, 0, 0);
                z = __builtin_amdgcn_mfma_f32_16x16x32_bf16(qf1, kf1, z, 0, 0, 0);
                s[nk] = z;
            }
            if (kb == niter - 1) {  // diagonal block: causal mask
                int rowb = q0 + w * 16 + quad * 4;
#pragma unroll
                for (int nk = 0; nk < 4; nk++) {
                    int kj = k0 + nk * 16 + row16;
#pragma unroll
                    for (int r = 0; r < 4; r++)
                        if (kj > rowb + r) s[nk][r] = -__builtin_inff();
                }
            }
#pragma unroll
            for (int nk = 0; nk < 4; nk++)
#pragma unroll
                for (int r = 0; r < 4; r++) {
                    float p = EXP2(s[nk][r]);
                    int qr = quad * 4 + r;
                    Psw[qr * 64 + (((nk * 2 + (row16 >> 3)) ^ (qr & 7)) * 8) + (row16 & 7)] =
                        f2bf(p);
                }
#pragma unroll
            for (int kk = 0; kk < 2; kk++) {
                s16x8 pf = *(const s16x8*)&Psw[row16 * 64 + (((kk * 4 + quad) ^ sw) * 8)];
#pragma unroll
                for (int nd = 0; nd < 4; nd++) {
                    s16x8 vf = *(const s16x8*)&Vc[(nd * 16 + row16) * 64 +
                                                  (((kk * 4 + quad) ^ sw) * 8)];
                    acc_o[nd] = __builtin_amdgcn_mfma_f32_16x16x32_bf16(pf, vf, acc_o[nd], 0, 0, 0);
                }
                acc_l = __builtin_amdgcn_mfma_f32_16x16x32_bf16(pf, ones, acc_l, 0, 0, 0);
            }
        }

        int t0 = q0 + w * 16 + quad * 4;
#pragma unroll
        for (int r = 0; r < 4; r++) {
            float inv = RCP(acc_l[r]);
#pragma unroll
            for (int nd = 0; nd < 4; nd++)
                y[((size_t)b * 2048 + t0 + r) * 1024 + h * 64 + nd * 16 + row16] =
                    f2bf(acc_o[nd][r] * inv);
        }
    }
}

extern "C" void kernel_launch(void* const* d_in, const int* in_sizes, int n_in,
                              void* d_out, int out_size, void* d_ws, size_t ws_size,
                              hipStream_t stream) {
    const float* x      = (const float*)d_in[0];
    const float* w_qkv  = (const float*)d_in[1];
    const float* b_qkv  = (const float*)d_in[2];
    const float* w_proj = (const float*)d_in[3];
    const float* b_proj = (const float*)d_in[4];
    float* out = (float*)d_out;

    u16* ws     = (u16*)d_ws;
    u16* x_bf   = ws;                               // 8192*1024
    u16* wqkvT  = x_bf  + (size_t)8192 * 1024;      // 3072*1024
    u16* wprojT = wqkvT + (size_t)3072 * 1024;      // 1024*1024
    u16* qkbuf  = wprojT + (size_t)1024 * 1024;     // 8192*2048 (Q|K)
    u16* vT     = qkbuf + (size_t)8192 * 2048;      // 4096*2048 (V transposed)
    u16* ybf    = vT    + (size_t)4096 * 2048;      // 8192*1024

    cast_f32_bf16<<<dim3(8192), dim3(256), 0, stream>>>(x, x_bf);
    transpose_cast<<<dim3(96, 32), dim3(32, 8), 0, stream>>>(w_qkv, wqkvT, 1024, 3072);
    transpose_cast<<<dim3(32, 32), dim3(32, 8), 0, stream>>>(w_proj, wprojT, 1024, 1024);
    gemm_bt64<1><<<dim3(24, 64), 256, 0, stream>>>(x_bf, wqkvT, b_qkv, (void*)qkbuf, vT, 8192, 3072, 1024);
    attn_kernel<<<dim3(16, 64), 256, 0, stream>>>(qkbuf, vT, ybf);
    gemm_bt64<0><<<dim3(8, 64), 256, 0, stream>>>(ybf, wprojT, b_proj, (void*)out, nullptr, 8192, 1024, 1024);
}

// Round 4
// 233.515 us; speedup vs baseline: 2.1132x; 1.1249x over previous
//
#include <hip/hip_runtime.h>

typedef unsigned short u16;
typedef unsigned int u32;
typedef unsigned long long u64;
typedef __attribute__((ext_vector_type(8))) short s16x8;
typedef __attribute__((ext_vector_type(4))) float f32x4;

#if __has_builtin(__builtin_amdgcn_exp2f)
#define EXP2(x) __builtin_amdgcn_exp2f(x)
#else
#define EXP2(x) __expf((x) * 0.69314718f)
#endif

#if __has_builtin(__builtin_amdgcn_rcpf)
#define RCP(x) __builtin_amdgcn_rcpf(x)
#else
#define RCP(x) (1.0f / (x))
#endif

#define GLL(gp, lp) __builtin_amdgcn_global_load_lds(                         \
    (const __attribute__((address_space(1))) unsigned int*)(const void*)(gp), \
    (__attribute__((address_space(3))) unsigned int*)(void*)(lp), 16, 0, 0)

__device__ __forceinline__ u16 f2bf(float f) {
    union { float f; u32 u; } v; v.f = f;
    u32 r = v.u + 0x7FFF + ((v.u >> 16) & 1);
    return (u16)(r >> 16);
}

__device__ __forceinline__ u16 f2bf_trunc(float f) {
    union { float f; u32 u; } v; v.f = f;
    return (u16)(v.u >> 16);
}

__device__ __forceinline__ float bf2f(u16 b) {
    union { u32 u; float f; } v; v.u = ((u32)b) << 16;
    return v.f;
}

__device__ __forceinline__ s16x8 scale_frag(s16x8 v, float s) {
    s16x8 o;
#pragma unroll
    for (int i = 0; i < 8; i++) o[i] = (short)f2bf(bf2f((u16)v[i]) * s);
    return o;
}

// ---------------- cast fp32 -> bf16 (contiguous) ----------------
__global__ __launch_bounds__(256) void cast_f32_bf16(const float* __restrict__ in,
                                                     u16* __restrict__ out) {
    size_t i = ((size_t)blockIdx.x * 256 + threadIdx.x) * 4;
    float4 f = *(const float4*)(in + i);
    u16 o[4] = { f2bf(f.x), f2bf(f.y), f2bf(f.z), f2bf(f.w) };
    *(unsigned long long*)(out + i) =
        (unsigned long long)o[0] | ((unsigned long long)o[1] << 16) |
        ((unsigned long long)o[2] << 32) | ((unsigned long long)o[3] << 48);
}

// ---------------- transpose + cast: in[rows][cols] f32 -> out[cols][rows] bf16 ----
__global__ __launch_bounds__(256) void transpose_cast(const float* __restrict__ in,
                                                      u16* __restrict__ out,
                                                      int rows, int cols) {
    __shared__ float tile[32][33];
    int c0 = blockIdx.x * 32, r0 = blockIdx.y * 32;
    int tx = threadIdx.x, ty = threadIdx.y; // 32 x 8
    for (int i = 0; i < 32; i += 8)
        tile[ty + i][tx] = in[(size_t)(r0 + ty + i) * cols + (c0 + tx)];
    __syncthreads();
    for (int i = 0; i < 32; i += 8)
        out[(size_t)(c0 + ty + i) * rows + (r0 + tx)] = f2bf(tile[tx][ty + i]);
}

// ---------------- GEMM: C = A[M][K] * BT[N][K]^T + bias, BK=64, XOR-swizzled LDS ---
// MODE 0: fp32 out to O1[M][N].
// MODE 1: QKV split -- col<2048 -> bf16 qk[M][2048]; col>=2048 -> vT via LDS transpose
template<int MODE>
__global__ __launch_bounds__(256, 4) void gemm_bt64(const u16* __restrict__ A,
                                                    const u16* __restrict__ BT,
                                                    const float* __restrict__ bias,
                                                    void* __restrict__ O1,
                                                    u16* __restrict__ vT,
                                                    int M, int N, int K) {
    __shared__ u16 SMEM[18432];  // 36864 B: K-loop uses 32 KB; epilogue scratch 36 KB
    u16* As = SMEM;
    u16* Bs = SMEM + 8192;
    int n0 = blockIdx.x * 128, m0 = blockIdx.y * 128;
    int tid = threadIdx.x, lane = tid & 63, w = tid >> 6;
    int row16 = lane & 15, quad = lane >> 4;
    int wm = (w >> 1) * 64, wn = (w & 1) * 64;
    f32x4 acc[4][4] = {};

    int lr = lane >> 3;            // row-in-8 of staged row
    int cswz = (lane & 7) ^ lr;    // swizzled source column chunk
    const u16* Ag = A + (size_t)(m0 + w * 32 + lr) * K + cswz * 8;
    const u16* Bg = BT + (size_t)(n0 + w * 32 + lr) * K + cswz * 8;
    u16* Asl = As + (w * 32) * 64;
    u16* Bsl = Bs + (w * 32) * 64;

    for (int k0 = 0; k0 < K; k0 += 64) {
        __syncthreads();
#pragma unroll
        for (int j = 0; j < 4; j++) {
            GLL(Ag + k0 + (size_t)j * 8 * K, Asl + j * 8 * 64);
            GLL(Bg + k0 + (size_t)j * 8 * K, Bsl + j * 8 * 64);
        }
        __syncthreads();
#pragma unroll
        for (int kk = 0; kk < 2; kk++) {
            s16x8 af[4], bf[4];
#pragma unroll
            for (int mi = 0; mi < 4; mi++)
                af[mi] = *(const s16x8*)&As[(wm + mi * 16 + row16) * 64 +
                                            (((kk * 4 + quad) ^ (row16 & 7)) * 8)];
#pragma unroll
            for (int ni = 0; ni < 4; ni++)
                bf[ni] = *(const s16x8*)&Bs[(wn + ni * 16 + row16) * 64 +
                                            (((kk * 4 + quad) ^ (row16 & 7)) * 8)];
#pragma unroll
            for (int mi = 0; mi < 4; mi++)
#pragma unroll
                for (int ni = 0; ni < 4; ni++)
                    acc[mi][ni] = __builtin_amdgcn_mfma_f32_16x16x32_bf16(
                        af[mi], bf[ni], acc[mi][ni], 0, 0, 0);
        }
    }

    if (MODE == 0) {
        float* O = (float*)O1;
#pragma unroll
        for (int ni = 0; ni < 4; ni++) {
            int col = n0 + wn + ni * 16 + row16;
            float bv = bias[col];
#pragma unroll
            for (int mi = 0; mi < 4; mi++)
#pragma unroll
                for (int r = 0; r < 4; r++)
                    O[(size_t)(m0 + wm + mi * 16 + quad * 4 + r) * N + col] =
                        acc[mi][ni][r] + bv;
        }
    } else if (n0 < 2048) {  // Q|K region (block-uniform)
        u16* qk = (u16*)O1;
#pragma unroll
        for (int ni = 0; ni < 4; ni++) {
            int col = n0 + wn + ni * 16 + row16;
            float bv = bias[col];
#pragma unroll
            for (int mi = 0; mi < 4; mi++)
#pragma unroll
                for (int r = 0; r < 4; r++)
                    qk[(size_t)(m0 + wm + mi * 16 + quad * 4 + r) * 2048 + col] =
                        f2bf(acc[mi][ni][r] + bv);
        }
    } else {  // V region: transpose via per-wave LDS scratch, coalesced 16B stores
        __syncthreads();                      // K-loop LDS reads done
        u16* scr = SMEM + w * 64 * 72;        // 64 rows (c) x 72-padded (t)
#pragma unroll
        for (int ni = 0; ni < 4; ni++) {
            float bv = bias[n0 + wn + ni * 16 + row16];
#pragma unroll
            for (int mi = 0; mi < 4; mi++)
#pragma unroll
                for (int r = 0; r < 4; r++)
                    scr[(ni * 16 + row16) * 72 + (mi * 16 + quad * 4 + r)] =
                        f2bf(acc[mi][ni][r] + bv);
        }
        __syncthreads();                      // drain LDS writes (lgkm)
        int r8 = lane >> 3, c8 = lane & 7;
        int vbase = (m0 >> 11) * 1024 + (n0 - 2048) + wn;  // b*1024 + c0
        int tb = (m0 & 2047) + wm;                         // t within batch
#pragma unroll
        for (int it = 0; it < 8; it++) {
            s16x8 vv = *(const s16x8*)&scr[(it * 8 + r8) * 72 + c8 * 8];
            *(s16x8*)&vT[(size_t)(vbase + it * 8 + r8) * 2048 + tb + c8 * 8] = vv;
        }
    }
}

// ---------------- flash attention (causal, no-max softmax, paired q-tiles) -------
// qk: [B*T][2048] bf16 (Q cols 0..1023, K cols 1024..2047)
// vT: [(b*1024 + h*64 + d)][2048] bf16 ; y: [B*T][1024] bf16
// flat grid 1024; decode keeps all 16 pair-blocks of one bh on XCD bh%8.
__global__ __launch_bounds__(256, 4) void attn_kernel(const u16* __restrict__ qk,
                                                      const u16* __restrict__ vT,
                                                      u16* __restrict__ y) {
    __shared__ u16 Kb[2][64 * 64];
    __shared__ u16 Vb[2][64 * 64];
    __shared__ u16 Ps[4 * 16 * 64];

    int tid = threadIdx.x, lane = tid & 63, w = tid >> 6;
    int row16 = lane & 15, quad = lane >> 4;
    int id = blockIdx.x;                 // 0..1023
    int xcd = id & 7, slot = id >> 3;
    int pairi = slot >> 3;               // 0..15
    int bh = ((slot & 7) << 3) | xcd;    // all pairi of bh land on XCD bh%8
    int b = bh >> 4, h = bh & 15;
    const u16* qkb = qk + (size_t)b * 2048 * 2048;
    const u16* vtb = vT + ((size_t)(b * 1024) + h * 64) * 2048;

    int lr = lane >> 3, cswz = (lane & 7) ^ lr;
    const u16* Kg = qkb + (size_t)(w * 16 + lr) * 2048 + 1024 + h * 64 + cswz * 8;
    const u16* Vg = vtb + (size_t)(w * 16 + lr) * 2048 + cswz * 8;
    u16* Psw = Ps + w * 1024;
    int sw = row16 & 7;

    s16x8 ones;
#pragma unroll
    for (int i = 0; i < 8; i++) ones[i] = (short)0x3F80;  // bf16 1.0
    const float qs = 0.125f * 1.44269504f;                // 1/sqrt(64) * log2(e)

    for (int half = 0; half < 2; half++) {
        int qt = half ? pairi : (31 - pairi);  // big tile first
        int q0 = qt * 64;
        int niter = qt + 1;

        int qrow = q0 + w * 16 + row16;
        const u16* qp = qkb + (size_t)qrow * 2048 + h * 64 + quad * 8;
        s16x8 qf0 = scale_frag(*(const s16x8*)qp, qs);
        s16x8 qf1 = scale_frag(*(const s16x8*)(qp + 32), qs);

        f32x4 acc_o[4] = {};
        f32x4 acc_l = {};

        __syncthreads();  // all waves done reading K/V buffers of previous half
#pragma unroll
        for (int j = 0; j < 2; j++) {  // prologue prefetch k-block 0 -> buf 0
            GLL(Kg + (size_t)j * 8 * 2048, Kb[0] + w * 16 * 64 + j * 8 * 64);
            GLL(Vg + (size_t)j * 8 * 2048, Vb[0] + w * 16 * 64 + j * 8 * 64);
        }

        for (int kb = 0; kb < niter; kb++) {
            int cur = kb & 1;
            __syncthreads();  // drains GLLs for cur + joins waves
            if (kb + 1 < niter) {
                int k1 = (kb + 1) * 64;
#pragma unroll
                for (int j = 0; j < 2; j++) {
                    GLL(Kg + (size_t)(k1 + j * 8) * 2048, Kb[cur ^ 1] + w * 16 * 64 + j * 8 * 64);
                    GLL(Vg + k1 + (size_t)j * 8 * 2048, Vb[cur ^ 1] + w * 16 * 64 + j * 8 * 64);
                }
            }
            const u16* Kc = Kb[cur];
            const u16* Vc = Vb[cur];
            int k0 = kb * 64;

            f32x4 s[4];
#pragma unroll
            for (int nk = 0; nk < 4; nk++) {
                s16x8 kf0 = *(const s16x8*)&Kc[(nk * 16 + row16) * 64 + ((quad ^ sw) * 8)];
                s16x8 kf1 = *(const s16x8*)&Kc[(nk * 16 + row16) * 64 + (((4 + quad) ^ sw) * 8)];
                f32x4 z = {};
                z = __builtin_amdgcn_mfma_f32_16x16x32_bf16(qf0, kf0, z, 0, 0, 0);
                z = __builtin_amdgcn_mfma_f32_16x16x32_bf16(qf1, kf1, z, 0, 0, 0);
                s[nk] = z;
            }
            if (kb == niter - 1) {  // diagonal block: causal mask
                int rowb = q0 + w * 16 + quad * 4;
#pragma unroll
                for (int nk = 0; nk < 4; nk++) {
                    int kj = k0 + nk * 16 + row16;
#pragma unroll
                    for (int r = 0; r < 4; r++)
                        if (kj > rowb + r) s[nk][r] = -__builtin_inff();
                }
            }
#pragma unroll
            for (int nk = 0; nk < 4; nk++)
#pragma unroll
                for (int r = 0; r < 4; r++) {
                    float p = EXP2(s[nk][r]);
                    int qr = quad * 4 + r;
                    Psw[qr * 64 + (((nk * 2 + (row16 >> 3)) ^ (qr & 7)) * 8) + (row16 & 7)] =
                        f2bf_trunc(p);
                }
#pragma unroll
            for (int kk = 0; kk < 2; kk++) {
                s16x8 pf = *(const s16x8*)&Psw[row16 * 64 + (((kk * 4 + quad) ^ sw) * 8)];
#pragma unroll
                for (int nd = 0; nd < 4; nd++) {
                    s16x8 vf = *(const s16x8*)&Vc[(nd * 16 + row16) * 64 +
                                                  (((kk * 4 + quad) ^ sw) * 8)];
                    acc_o[nd] = __builtin_amdgcn_mfma_f32_16x16x32_bf16(pf, vf, acc_o[nd], 0, 0, 0);
                }
                acc_l = __builtin_amdgcn_mfma_f32_16x16x32_bf16(pf, ones, acc_l, 0, 0, 0);
            }
        }

        int t0 = q0 + w * 16 + quad * 4;
#pragma unroll
        for (int r = 0; r < 4; r++) {
            float inv = RCP(acc_l[r]);
#pragma unroll
            for (int nd = 0; nd < 4; nd++)
                y[((size_t)b * 2048 + t0 + r) * 1024 + h * 64 + nd * 16 + row16] =
                    f2bf(acc_o[nd][r] * inv);
        }
    }
}

extern "C" void kernel_launch(void* const* d_in, const int* in_sizes, int n_in,
                              void* d_out, int out_size, void* d_ws, size_t ws_size,
                              hipStream_t stream) {
    const float* x      = (const float*)d_in[0];
    const float* w_qkv  = (const float*)d_in[1];
    const float* b_qkv  = (const float*)d_in[2];
    const float* w_proj = (const float*)d_in[3];
    const float* b_proj = (const float*)d_in[4];
    float* out = (float*)d_out;

    u16* ws     = (u16*)d_ws;
    u16* x_bf   = ws;                               // 8192*1024
    u16* wqkvT  = x_bf  + (size_t)8192 * 1024;      // 3072*1024
    u16* wprojT = wqkvT + (size_t)3072 * 1024;      // 1024*1024
    u16* qkbuf  = wprojT + (size_t)1024 * 1024;     // 8192*2048 (Q|K)
    u16* vT     = qkbuf + (size_t)8192 * 2048;      // 4096*2048 (V transposed)
    u16* ybf    = vT    + (size_t)4096 * 2048;      // 8192*1024

    cast_f32_bf16<<<dim3(8192), dim3(256), 0, stream>>>(x, x_bf);
    transpose_cast<<<dim3(96, 32), dim3(32, 8), 0, stream>>>(w_qkv, wqkvT, 1024, 3072);
    transpose_cast<<<dim3(32, 32), dim3(32, 8), 0, stream>>>(w_proj, wprojT, 1024, 1024);
    gemm_bt64<1><<<dim3(24, 64), 256, 0, stream>>>(x_bf, wqkvT, b_qkv, (void*)qkbuf, vT, 8192, 3072, 1024);
    attn_kernel<<<dim3(1024), 256, 0, stream>>>(qkbuf, vT, ybf);
    gemm_bt64<0><<<dim3(8, 64), 256, 0, stream>>>(ybf, wprojT, b_proj, (void*)out, nullptr, 8192, 1024, 1024);
}

// Round 5
// 230.720 us; speedup vs baseline: 2.1388x; 1.0121x over previous
//
#include <hip/hip_runtime.h>

typedef unsigned short u16;
typedef unsigned int u32;
typedef unsigned long long u64;
typedef __attribute__((ext_vector_type(8))) short s16x8;
typedef __attribute__((ext_vector_type(4))) float f32x4;

#if __has_builtin(__builtin_amdgcn_exp2f)
#define EXP2(x) __builtin_amdgcn_exp2f(x)
#else
#define EXP2(x) __expf((x) * 0.69314718f)
#endif

#if __has_builtin(__builtin_amdgcn_rcpf)
#define RCP(x) __builtin_amdgcn_rcpf(x)
#else
#define RCP(x) (1.0f / (x))
#endif

#define GLL(gp, lp) __builtin_amdgcn_global_load_lds(                         \
    (const __attribute__((address_space(1))) unsigned int*)(const void*)(gp), \
    (__attribute__((address_space(3))) unsigned int*)(void*)(lp), 16, 0, 0)

__device__ __forceinline__ u16 f2bf(float f) {
    union { float f; u32 u; } v; v.f = f;
    u32 r = v.u + 0x7FFF + ((v.u >> 16) & 1);
    return (u16)(r >> 16);
}

__device__ __forceinline__ u32 pack2_trunc(float a, float b) {
    union { float f; u32 u; } x, y; x.f = a; y.f = b;
    return (x.u >> 16) | (y.u & 0xFFFF0000u);
}

__device__ __forceinline__ float bf2f(u16 b) {
    union { u32 u; float f; } v; v.u = ((u32)b) << 16;
    return v.f;
}

__device__ __forceinline__ s16x8 scale_frag(s16x8 v, float s) {
    s16x8 o;
#pragma unroll
    for (int i = 0; i < 8; i++) o[i] = (short)f2bf(bf2f((u16)v[i]) * s);
    return o;
}

// ---------------- cast fp32 -> bf16 (contiguous) ----------------
__global__ __launch_bounds__(256) void cast_f32_bf16(const float* __restrict__ in,
                                                     u16* __restrict__ out) {
    size_t i = ((size_t)blockIdx.x * 256 + threadIdx.x) * 4;
    float4 f = *(const float4*)(in + i);
    u16 o[4] = { f2bf(f.x), f2bf(f.y), f2bf(f.z), f2bf(f.w) };
    *(unsigned long long*)(out + i) =
        (unsigned long long)o[0] | ((unsigned long long)o[1] << 16) |
        ((unsigned long long)o[2] << 32) | ((unsigned long long)o[3] << 48);
}

// ---------------- transpose + cast: in[rows][cols] f32 -> out[cols][rows] bf16 ----
__global__ __launch_bounds__(256) void transpose_cast(const float* __restrict__ in,
                                                      u16* __restrict__ out,
                                                      int rows, int cols) {
    __shared__ float tile[32][33];
    int c0 = blockIdx.x * 32, r0 = blockIdx.y * 32;
    int tx = threadIdx.x, ty = threadIdx.y; // 32 x 8
    for (int i = 0; i < 32; i += 8)
        tile[ty + i][tx] = in[(size_t)(r0 + ty + i) * cols + (c0 + tx)];
    __syncthreads();
    for (int i = 0; i < 32; i += 8)
        out[(size_t)(c0 + ty + i) * rows + (r0 + tx)] = f2bf(tile[tx][ty + i]);
}

// ---------------- GEMM: C = A[M][K] * BT[N][K]^T + bias, BK=64, XOR-swizzled LDS ---
// Flat grid with XCD m-stripe swizzle: m0 = (xcd*8 + mi8)*128 keeps each XCD's
// A-stripe (2 MB) resident in its private L2. Requires M = 8192 (64 m-blocks).
// MODE 0: fp32 out to O1[M][N].
// MODE 1: QKV split -- col<2048 -> bf16 qk[M][2048]; col>=2048 -> vT via LDS transpose
template<int MODE, int NB>
__global__ __launch_bounds__(256, 4) void gemm_bt64(const u16* __restrict__ A,
                                                    const u16* __restrict__ BT,
                                                    const float* __restrict__ bias,
                                                    void* __restrict__ O1,
                                                    u16* __restrict__ vT,
                                                    int M, int N, int K) {
    __shared__ u16 SMEM[18432];  // 36864 B: K-loop uses 32 KB; epilogue scratch 36 KB
    u16* As = SMEM;
    u16* Bs = SMEM + 8192;
    int id = blockIdx.x;
    int xcd = id & 7, s = id >> 3;
    int ni = s % NB, mi8 = s / NB;
    int n0 = ni * 128, m0 = (xcd * 8 + mi8) * 128;
    int tid = threadIdx.x, lane = tid & 63, w = tid >> 6;
    int row16 = lane & 15, quad = lane >> 4;
    int wm = (w >> 1) * 64, wn = (w & 1) * 64;
    f32x4 acc[4][4] = {};

    int lr = lane >> 3;            // row-in-8 of staged row
    int cswz = (lane & 7) ^ lr;    // swizzled source column chunk
    const u16* Ag = A + (size_t)(m0 + w * 32 + lr) * K + cswz * 8;
    const u16* Bg = BT + (size_t)(n0 + w * 32 + lr) * K + cswz * 8;
    u16* Asl = As + (w * 32) * 64;
    u16* Bsl = Bs + (w * 32) * 64;

    for (int k0 = 0; k0 < K; k0 += 64) {
        __syncthreads();
#pragma unroll
        for (int j = 0; j < 4; j++) {
            GLL(Ag + k0 + (size_t)j * 8 * K, Asl + j * 8 * 64);
            GLL(Bg + k0 + (size_t)j * 8 * K, Bsl + j * 8 * 64);
        }
        __syncthreads();
#pragma unroll
        for (int kk = 0; kk < 2; kk++) {
            s16x8 af[4], bf[4];
#pragma unroll
            for (int mi = 0; mi < 4; mi++)
                af[mi] = *(const s16x8*)&As[(wm + mi * 16 + row16) * 64 +
                                            (((kk * 4 + quad) ^ (row16 & 7)) * 8)];
#pragma unroll
            for (int ni2 = 0; ni2 < 4; ni2++)
                bf[ni2] = *(const s16x8*)&Bs[(wn + ni2 * 16 + row16) * 64 +
                                             (((kk * 4 + quad) ^ (row16 & 7)) * 8)];
#pragma unroll
            for (int mi = 0; mi < 4; mi++)
#pragma unroll
                for (int ni2 = 0; ni2 < 4; ni2++)
                    acc[mi][ni2] = __builtin_amdgcn_mfma_f32_16x16x32_bf16(
                        af[mi], bf[ni2], acc[mi][ni2], 0, 0, 0);
        }
    }

    if (MODE == 0) {
        float* O = (float*)O1;
#pragma unroll
        for (int ni2 = 0; ni2 < 4; ni2++) {
            int col = n0 + wn + ni2 * 16 + row16;
            float bv = bias[col];
#pragma unroll
            for (int mi = 0; mi < 4; mi++)
#pragma unroll
                for (int r = 0; r < 4; r++)
                    O[(size_t)(m0 + wm + mi * 16 + quad * 4 + r) * N + col] =
                        acc[mi][ni2][r] + bv;
        }
    } else if (n0 < 2048) {  // Q|K region (block-uniform)
        u16* qk = (u16*)O1;
#pragma unroll
        for (int ni2 = 0; ni2 < 4; ni2++) {
            int col = n0 + wn + ni2 * 16 + row16;
            float bv = bias[col];
#pragma unroll
            for (int mi = 0; mi < 4; mi++)
#pragma unroll
                for (int r = 0; r < 4; r++)
                    qk[(size_t)(m0 + wm + mi * 16 + quad * 4 + r) * 2048 + col] =
                        f2bf(acc[mi][ni2][r] + bv);
        }
    } else {  // V region: transpose via per-wave LDS scratch, coalesced 16B stores
        __syncthreads();                      // K-loop LDS reads done
        u16* scr = SMEM + w * 64 * 72;        // 64 rows (c) x 72-padded (t)
#pragma unroll
        for (int ni2 = 0; ni2 < 4; ni2++) {
            float bv = bias[n0 + wn + ni2 * 16 + row16];
#pragma unroll
            for (int mi = 0; mi < 4; mi++)
#pragma unroll
                for (int r = 0; r < 4; r++)
                    scr[(ni2 * 16 + row16) * 72 + (mi * 16 + quad * 4 + r)] =
                        f2bf(acc[mi][ni2][r] + bv);
        }
        __syncthreads();                      // drain LDS writes (lgkm)
        int r8 = lane >> 3, c8 = lane & 7;
        int vbase = (m0 >> 11) * 1024 + (n0 - 2048) + wn;  // b*1024 + c0
        int tb = (m0 & 2047) + wm;                         // t within batch
#pragma unroll
        for (int it = 0; it < 8; it++) {
            s16x8 vv = *(const s16x8*)&scr[(it * 8 + r8) * 72 + c8 * 8];
            *(s16x8*)&vT[(size_t)(vbase + it * 8 + r8) * 2048 + tb + c8 * 8] = vv;
        }
    }
}

// ---------------- flash attention (causal, no-max softmax, S^T form) -------------
// qk: [B*T][2048] bf16 (Q cols 0..1023, K cols 1024..2047)
// vT: [(b*1024 + h*64 + d)][2048] bf16 ; y: [B*T][1024] bf16
// 128-row q-tiles, 32 rows/wave. S^T = K*Q^T so C-layout gives 4 consecutive keys
// per lane -> packed b64 P writes. 512 blocks: pair (i, 15-i) -> uniform 34 iters;
// XCD decode keeps all blocks of one bh on XCD bh%8.
__global__ __launch_bounds__(256, 2) void attn_kernel(const u16* __restrict__ qk,
                                                      const u16* __restrict__ vT,
                                                      u16* __restrict__ y) {
    __shared__ u16 Kb[2][4096];
    __shared__ u16 Vb[2][4096];
    __shared__ u16 Ps[4][2048];   // per wave: 2 mi x 16 rows x 64 keys

    int tid = threadIdx.x, lane = tid & 63, w = tid >> 6;
    int row16 = lane & 15, quad = lane >> 4;
    int id = blockIdx.x;                 // 0..511
    int xcd = id & 7, slot = id >> 3;
    int pairi = slot >> 3;               // 0..7
    int bh = ((slot & 7) << 3) | xcd;    // all blocks of bh on XCD bh%8
    int b = bh >> 4, h = bh & 15;
    const u16* qkb = qk + (size_t)b * 2048 * 2048;
    const u16* vtb = vT + ((size_t)(b * 1024) + h * 64) * 2048;

    int lr = lane >> 3, cswz = (lane & 7) ^ lr;
    const u16* Kg = qkb + (size_t)(w * 16 + lr) * 2048 + 1024 + h * 64 + cswz * 8;
    const u16* Vg = vtb + (size_t)(w * 16 + lr) * 2048 + cswz * 8;
    u16* Psw = Ps[w];
    int sw = row16 & 7;

    s16x8 ones;
#pragma unroll
    for (int i = 0; i < 8; i++) ones[i] = (short)0x3F80;  // bf16 1.0
    const float qs = 0.125f * 1.44269504f;                // 1/sqrt(64) * log2(e)

    for (int half = 0; half < 2; half++) {
        int qt = half ? pairi : (15 - pairi);  // big tile first
        int q0 = qt * 128;
        int niter = 2 * qt + 2;
        int qw = q0 + w * 32;                  // this wave's first q-row

        s16x8 qf[2][2];
#pragma unroll
        for (int mi = 0; mi < 2; mi++) {
            const u16* qp = qkb + (size_t)(qw + mi * 16 + row16) * 2048 + h * 64 + quad * 8;
            qf[mi][0] = scale_frag(*(const s16x8*)qp, qs);
            qf[mi][1] = scale_frag(*(const s16x8*)(qp + 32), qs);
        }

        f32x4 acc_o[2][4] = {};
        f32x4 acc_l[2] = {};

        __syncthreads();  // previous half's reads of Kb/Vb complete
#pragma unroll
        for (int j = 0; j < 2; j++) {  // prologue prefetch k-block 0 -> buf 0
            GLL(Kg + (size_t)j * 8 * 2048, Kb[0] + w * 16 * 64 + j * 8 * 64);
            GLL(Vg + (size_t)j * 8 * 2048, Vb[0] + w * 16 * 64 + j * 8 * 64);
        }

        for (int kb = 0; kb < niter; kb++) {
            int cur = kb & 1;
            __syncthreads();  // drains GLLs for cur + joins waves
            if (kb + 1 < niter) {
                int k1 = (kb + 1) * 64;
#pragma unroll
                for (int j = 0; j < 2; j++) {
                    GLL(Kg + (size_t)(k1 + j * 8) * 2048, Kb[cur ^ 1] + w * 16 * 64 + j * 8 * 64);
                    GLL(Vg + k1 + (size_t)j * 8 * 2048, Vb[cur ^ 1] + w * 16 * 64 + j * 8 * 64);
                }
            }
            int k0 = kb * 64;
            if (k0 > qw + 31) continue;  // wave-uniform: fully-masked for this wave
            const u16* Kc = Kb[cur];
            const u16* Vc = Vb[cur];

            // S^T = K Q^T : lane holds (q=row16 fixed, keys quad*4+r of tile nk)
            f32x4 sc[2][4];
#pragma unroll
            for (int nk = 0; nk < 4; nk++) {
                s16x8 kf0 = *(const s16x8*)&Kc[(nk * 16 + row16) * 64 + ((quad ^ sw) * 8)];
                s16x8 kf1 = *(const s16x8*)&Kc[(nk * 16 + row16) * 64 + (((4 + quad) ^ sw) * 8)];
#pragma unroll
                for (int mi = 0; mi < 2; mi++) {
                    f32x4 z = {};
                    z = __builtin_amdgcn_mfma_f32_16x16x32_bf16(kf0, qf[mi][0], z, 0, 0, 0);
                    z = __builtin_amdgcn_mfma_f32_16x16x32_bf16(kf1, qf[mi][1], z, 0, 0, 0);
                    sc[mi][nk] = z;
                }
            }
            if (k0 + 63 > qw) {  // diagonal region: causal mask (key > q -> -inf)
#pragma unroll
                for (int mi = 0; mi < 2; mi++) {
                    int qg = qw + mi * 16 + row16;
#pragma unroll
                    for (int nk = 0; nk < 4; nk++) {
                        int kbase = k0 + nk * 16 + quad * 4;
#pragma unroll
                        for (int r = 0; r < 4; r++)
                            if (kbase + r > qg) sc[mi][nk][r] = -__builtin_inff();
                    }
                }
            }
            // exp2 -> P[q][key] rows in LDS via packed b64 (XOR-swizzled 16B units)
#pragma unroll
            for (int mi = 0; mi < 2; mi++)
#pragma unroll
                for (int nk = 0; nk < 4; nk++) {
                    float p0 = EXP2(sc[mi][nk][0]);
                    float p1 = EXP2(sc[mi][nk][1]);
                    float p2 = EXP2(sc[mi][nk][2]);
                    float p3 = EXP2(sc[mi][nk][3]);
                    u32 w0 = pack2_trunc(p0, p1);
                    u32 w1 = pack2_trunc(p2, p3);
                    int u = nk * 2 + (quad >> 1);
                    int eo = ((u ^ sw) * 8) + (quad & 1) * 4;
                    *(u64*)&Psw[mi * 1024 + row16 * 64 + eo] = (u64)w0 | ((u64)w1 << 32);
                }
            // P (A-layout) x V^T (B-layout); row-sums via ones-MFMA
#pragma unroll
            for (int kk = 0; kk < 2; kk++) {
                int co = ((kk * 4 + quad) ^ sw) * 8;
                s16x8 pf0 = *(const s16x8*)&Psw[row16 * 64 + co];
                s16x8 pf1 = *(const s16x8*)&Psw[1024 + row16 * 64 + co];
#pragma unroll
                for (int nd = 0; nd < 4; nd++) {
                    s16x8 vf = *(const s16x8*)&Vc[(nd * 16 + row16) * 64 + co];
                    acc_o[0][nd] = __builtin_amdgcn_mfma_f32_16x16x32_bf16(pf0, vf, acc_o[0][nd], 0, 0, 0);
                    acc_o[1][nd] = __builtin_amdgcn_mfma_f32_16x16x32_bf16(pf1, vf, acc_o[1][nd], 0, 0, 0);
                }
                acc_l[0] = __builtin_amdgcn_mfma_f32_16x16x32_bf16(pf0, ones, acc_l[0], 0, 0, 0);
                acc_l[1] = __builtin_amdgcn_mfma_f32_16x16x32_bf16(pf1, ones, acc_l[1], 0, 0, 0);
            }
        }

        // epilogue: O / l -> y bf16
#pragma unroll
        for (int mi = 0; mi < 2; mi++) {
            int t0 = qw + mi * 16 + quad * 4;
#pragma unroll
            for (int r = 0; r < 4; r++) {
                float inv = RCP(acc_l[mi][r]);
#pragma unroll
                for (int nd = 0; nd < 4; nd++)
                    y[((size_t)b * 2048 + t0 + r) * 1024 + h * 64 + nd * 16 + row16] =
                        f2bf(acc_o[mi][nd][r] * inv);
            }
        }
    }
}

extern "C" void kernel_launch(void* const* d_in, const int* in_sizes, int n_in,
                              void* d_out, int out_size, void* d_ws, size_t ws_size,
                              hipStream_t stream) {
    const float* x      = (const float*)d_in[0];
    const float* w_qkv  = (const float*)d_in[1];
    const float* b_qkv  = (const float*)d_in[2];
    const float* w_proj = (const float*)d_in[3];
    const float* b_proj = (const float*)d_in[4];
    float* out = (float*)d_out;

    u16* ws     = (u16*)d_ws;
    u16* x_bf   = ws;                               // 8192*1024
    u16* wqkvT  = x_bf  + (size_t)8192 * 1024;      // 3072*1024
    u16* wprojT = wqkvT + (size_t)3072 * 1024;      // 1024*1024
    u16* qkbuf  = wprojT + (size_t)1024 * 1024;     // 8192*2048 (Q|K)
    u16* vT     = qkbuf + (size_t)8192 * 2048;      // 4096*2048 (V transposed)
    u16* ybf    = vT    + (size_t)4096 * 2048;      // 8192*1024

    cast_f32_bf16<<<dim3(8192), dim3(256), 0, stream>>>(x, x_bf);
    transpose_cast<<<dim3(96, 32), dim3(32, 8), 0, stream>>>(w_qkv, wqkvT, 1024, 3072);
    transpose_cast<<<dim3(32, 32), dim3(32, 8), 0, stream>>>(w_proj, wprojT, 1024, 1024);
    gemm_bt64<1, 24><<<dim3(1536), 256, 0, stream>>>(x_bf, wqkvT, b_qkv, (void*)qkbuf, vT, 8192, 3072, 1024);
    attn_kernel<<<dim3(512), 256, 0, stream>>>(qkbuf, vT, ybf);
    gemm_bt64<0, 8><<<dim3(512), 256, 0, stream>>>(ybf, wprojT, b_proj, (void*)out, nullptr, 8192, 1024, 1024);
}